// Round 3
// baseline (304.884 us; speedup 1.0000x reference)
//
#include <hip/hip_runtime.h>

#define GS 128
#define GS3 (GS*GS*GS)
#define NPTS 150000
#define NBATCH 2
#define BN_TOT (NBATCH*NPTS)       // 300000
#define BN_PAD 300288              // 782 conv blocks * 384 pts
#define EPS 1e-5f

#define CONV_BLOCKS 782            // 4 waves/block, 96 pts/wave
#define PREP_BLOCKS 9375           // BN_TOT*8/256

// ws layout (total ~87.9 MB)
#define OFF_GRID   0ull
#define SZ_GRID    ((size_t)NBATCH*GS3*4)            // 16,777,216
#define OFF_WFRAG  (OFF_GRID + SZ_GRID)
#define SZ_WFRAG   ((size_t)27*4096*2)               // 221,184
#define OFF_STATS  (OFF_WFRAG + SZ_WFRAG)
#define OFF_FB16   (OFF_STATS + 512)
#define SZ_FB16    ((size_t)BN_PAD*64*2)             // 38,436,864
#define OFF_IDS    (OFF_FB16 + SZ_FB16)
#define SZ_IDS     ((size_t)27*BN_PAD*4)             // 32,431,104

typedef __attribute__((ext_vector_type(8))) short bf16x8;
typedef __attribute__((ext_vector_type(4))) float f32x4;

__device__ __forceinline__ short f2bf(float f) {
    union { float f; unsigned u; } v; v.f = f;
    unsigned rr = v.u + 0x7fffu + ((v.u >> 16) & 1u);   // RNE
    return (short)(rr >> 16);
}

// ---------- kernel 1: scatter max pid into dense grid ----------
__global__ __launch_bounds__(256) void k_scatter(const int* __restrict__ coords,
                                                 int* __restrict__ grid) {
    int p = blockIdx.x * 256 + threadIdx.x;
    if (p >= BN_TOT) return;
    int b = p / NPTS;
    int x = coords[p*3+0], y = coords[p*3+1], z = coords[p*3+2];
    atomicMax(&grid[((b*GS + x)*GS + y)*GS + z], p);
}

// ---------- kernel 2: weight -> bf16 MFMA B-fragments ----------
// wfrag ushort index ((((k*2+c)*4 + tt)*64 + lane)*8 + i)
//   holds W[k][ c*32 + (lane>>4)*8 + i ][ tt*16 + (lane&15) ]
__global__ __launch_bounds__(256) void k_prefrag(const float* __restrict__ w,
                                                 short* __restrict__ wfrag) {
    int t = blockIdx.x * 256 + threadIdx.x;
    if (t >= 27*2*4*64*8) return;
    int i    = t & 7;
    int lane = (t >> 3) & 63;
    int tt   = (t >> 9) & 3;
    int c    = (t >> 11) & 1;
    int k    = t >> 12;
    int kk = c*32 + (lane >> 4)*8 + i;
    int co = tt*16 + (lane & 15);
    wfrag[t] = f2bf(w[(k*64 + kk)*64 + co]);
}

// ---------- kernel 3: fused feats->bf16 + rulebook ids ----------
__global__ __launch_bounds__(256) void k_prep(const float* __restrict__ feats,
                                              const int* __restrict__ coords,
                                              const int* __restrict__ grid,
                                              ushort* __restrict__ fb16,
                                              int* __restrict__ ids) {
    int gt = blockIdx.x*256 + threadIdx.x;
    // part 1: bf16 convert (8 floats/thread, coalesced)
    if (gt < BN_TOT*8) {
        const float4* s = (const float4*)(feats + (size_t)gt*8);
        float4 x = s[0], y = s[1];
        ushort4 lo = { (ushort)f2bf(x.x),(ushort)f2bf(x.y),(ushort)f2bf(x.z),(ushort)f2bf(x.w) };
        ushort4 hi = { (ushort)f2bf(y.x),(ushort)f2bf(y.y),(ushort)f2bf(y.z),(ushort)f2bf(y.w) };
        ushort4* d = (ushort4*)(fb16 + (size_t)gt*8);
        d[0] = lo; d[1] = hi;
    }
    // part 2: 27 rulebook ids for point gt (k-major, coalesced writes)
    int p = gt;
    if (p < BN_PAD) {
        if (p < BN_TOT) {
            int cx = coords[p*3+0], cy = coords[p*3+1], cz = coords[p*3+2];
            const int* gb = grid + (p >= NPTS ? GS3 : 0);
            #pragma unroll
            for (int k = 0; k < 27; ++k) {            // compile-time dx/dy/dz
                int dx = k/9 - 1, dy = (k/3)%3 - 1, dz = k%3 - 1;
                int nx = cx+dx, ny = cy+dy, nz = cz+dz;
                int id = -1;
                if (((unsigned)nx < 128u) & ((unsigned)ny < 128u) & ((unsigned)nz < 128u))
                    id = gb[(nx<<14) + (ny<<7) + nz];
                ids[(size_t)k*BN_PAD + p] = id;
            }
        } else {
            #pragma unroll
            for (int k = 0; k < 27; ++k) ids[(size_t)k*BN_PAD + p] = -1;
        }
    }
}

// ---------- kernel 4: barrier-free gathered MFMA conv ----------
// 4 waves/block, wave = 96 pts x 64 cout (6 MFMA row-tiles).
// B-frags from global (L2-hot, 8KB/k). Single-buffered regs, WAR-ordered
// software pipeline: [MFMA X | reload aX(k+1)] [MFMA Y | reload aY(k+1),
// B(k+1), ids(k+2)]. Invalid ids -> pre-zeroed row BN_TOT of fb16.
__global__ __launch_bounds__(256, 2) void k_conv(
    const ushort* __restrict__ fb16,
    const int* __restrict__ ids,
    const ushort* __restrict__ wfrag,
    float* __restrict__ out,
    float* __restrict__ gstats)
{
    __shared__ float bsum[64], bsq[64];
    const int tid  = threadIdx.x;
    const int lane = tid & 63;
    const int wv   = tid >> 6;
    const int r    = lane & 15;
    const int seg  = lane >> 4;
    const int p0   = (blockIdx.x*4 + wv) * 96;

#define LDA2(dst, idv) { int sel_ = (idv) < 0 ? BN_TOT : (idv);                 \
        const ushort* ap_ = fb16 + (size_t)sel_*64 + seg*8;                     \
        dst[0] = *(const bf16x8*)(ap_); dst[1] = *(const bf16x8*)(ap_ + 32); }
#define LDB(kk) { const bf16x8* wp_ = (const bf16x8*)(wfrag + (size_t)(kk)*4096); \
        _Pragma("unroll") for (int f_ = 0; f_ < 8; ++f_) bb[f_] = wp_[f_*64 + lane]; }
#define LDIDS(dst, kk) { const int* ip_ = ids + (size_t)(kk)*BN_PAD + p0 + r;   \
        _Pragma("unroll") for (int t_ = 0; t_ < 6; ++t_) dst[t_] = ip_[16*t_]; }

    f32x4 acc[6][4];
    #pragma unroll
    for (int t = 0; t < 6; ++t)
        #pragma unroll
        for (int q = 0; q < 4; ++q) acc[t][q] = (f32x4){0,0,0,0};

    bf16x8 aX[3][2], aY[3][2], bb[8];
    int idc[6], idn[6];

    // prologue
    LDIDS(idc, 0);
    LDB(0);
    #pragma unroll
    for (int t = 0; t < 3; ++t) LDA2(aX[t], idc[t]);
    #pragma unroll
    for (int t = 0; t < 3; ++t) LDA2(aY[t], idc[t+3]);
    LDIDS(idn, 1);

    #pragma unroll 1
    for (int k = 0; k < 27; ++k) {
        // X half: tiles 0..2
        #pragma unroll
        for (int t = 0; t < 3; ++t)
            #pragma unroll
            for (int q = 0; q < 4; ++q) {
                acc[t][q] = __builtin_amdgcn_mfma_f32_16x16x32_bf16(aX[t][0], bb[q],   acc[t][q], 0,0,0);
                acc[t][q] = __builtin_amdgcn_mfma_f32_16x16x32_bf16(aX[t][1], bb[4+q], acc[t][q], 0,0,0);
            }
        #pragma unroll
        for (int t = 0; t < 3; ++t) LDA2(aX[t], idn[t]);      // A(k+1) X (WAR after X-MFMAs)
        // Y half: tiles 3..5
        #pragma unroll
        for (int t = 0; t < 3; ++t)
            #pragma unroll
            for (int q = 0; q < 4; ++q) {
                acc[3+t][q] = __builtin_amdgcn_mfma_f32_16x16x32_bf16(aY[t][0], bb[q],   acc[3+t][q], 0,0,0);
                acc[3+t][q] = __builtin_amdgcn_mfma_f32_16x16x32_bf16(aY[t][1], bb[4+q], acc[3+t][q], 0,0,0);
            }
        #pragma unroll
        for (int t = 0; t < 3; ++t) LDA2(aY[t], idn[t+3]);    // A(k+1) Y
        int kb = (k < 26) ? k+1 : 26;
        LDB(kb);                                              // B(k+1) (WAR after Y-MFMAs)
        int k2 = (k < 25) ? k+2 : 26;
        LDIDS(idn, k2);                                       // ids(k+2) (WAR after aY reload)
    }

    // epilogue: stores. C/D layout: col = lane&15 (+16q), row-in-tile = seg*4+j
    #pragma unroll
    for (int t = 0; t < 6; ++t) {
        #pragma unroll
        for (int j = 0; j < 4; ++j) {
            int g = p0 + 16*t + seg*4 + j;
            if (g < BN_TOT) {
                float* ob = out + (size_t)g*64 + r;
                ob[ 0] = acc[t][0][j];
                ob[16] = acc[t][1][j];
                ob[32] = acc[t][2][j];
                ob[48] = acc[t][3][j];
            }
        }
    }

    // fused stats: per-channel sum / sumsq (pad rows are exactly zero)
    if (tid < 64) { bsum[tid] = 0.f; bsq[tid] = 0.f; }
    __syncthreads();
    #pragma unroll
    for (int q = 0; q < 4; ++q) {
        float s = 0.f, sq = 0.f;
        #pragma unroll
        for (int t = 0; t < 6; ++t)
            #pragma unroll
            for (int j = 0; j < 4; ++j) { float v = acc[t][q][j]; s += v; sq += v*v; }
        atomicAdd(&bsum[q*16 + r], s);
        atomicAdd(&bsq [q*16 + r], sq);
    }
    __syncthreads();
    if (tid < 64) { atomicAdd(&gstats[tid], bsum[tid]); atomicAdd(&gstats[64+tid], bsq[tid]); }
#undef LDA2
#undef LDB
#undef LDIDS
}

// ---------- kernel 5: normalize + affine + ReLU, in place ----------
__global__ __launch_bounds__(256) void k_norm(float* __restrict__ out,
                                              const float* __restrict__ stats,
                                              const float* __restrict__ gamma,
                                              const float* __restrict__ beta) {
    int i = blockIdx.x*256 + threadIdx.x;
    const int n4 = BN_TOT*16;
    if (i >= n4) return;
    float4 v = ((const float4*)out)[i];
    int ch = (i & 15) * 4;
    float o[4] = {v.x, v.y, v.z, v.w};
    float rp[4];
    #pragma unroll
    for (int j = 0; j < 4; ++j) {
        int c = ch + j;
        float mean = stats[c] * (1.f/BN_TOT);
        float var  = stats[64+c] * (1.f/BN_TOT) - mean*mean;
        float y = (o[j] - mean) * rsqrtf(var + EPS) * gamma[c] + beta[c];
        rp[j] = fmaxf(y, 0.f);
    }
    float4 rv; rv.x = rp[0]; rv.y = rp[1]; rv.z = rp[2]; rv.w = rp[3];
    ((float4*)out)[i] = rv;
}

extern "C" void kernel_launch(void* const* d_in, const int* in_sizes, int n_in,
                              void* d_out, int out_size, void* d_ws, size_t ws_size,
                              hipStream_t stream) {
    const float* feats  = (const float*)d_in[0];
    const int*   coords = (const int*)d_in[1];
    const float* weight = (const float*)d_in[2];
    const float* gamma  = (const float*)d_in[3];
    const float* beta   = (const float*)d_in[4];
    float* out = (float*)d_out;

    char*   ws    = (char*)d_ws;
    int*    grid  = (int*)(ws + OFF_GRID);
    short*  wfrag = (short*)(ws + OFF_WFRAG);
    float*  stats = (float*)(ws + OFF_STATS);
    ushort* fb16  = (ushort*)(ws + OFF_FB16);
    int*    idbuf = (int*)(ws + OFF_IDS);

    hipMemsetAsync(grid, 0xFF, SZ_GRID, stream);                       // cells = -1
    hipMemsetAsync(stats, 0, 512, stream);
    hipMemsetAsync(fb16 + (size_t)BN_TOT*64, 0,
                   (size_t)(BN_PAD - BN_TOT)*128, stream);             // zero row(s)

    k_scatter<<<(BN_TOT + 255)/256, 256, 0, stream>>>(coords, grid);
    k_prefrag<<<(27*2*4*64*8)/256, 256, 0, stream>>>(weight, wfrag);
    k_prep<<<PREP_BLOCKS, 256, 0, stream>>>(feats, coords, grid, fb16, idbuf);
    k_conv<<<CONV_BLOCKS, 256, 0, stream>>>(fb16, idbuf, (const ushort*)wfrag,
                                            out, stats);
    k_norm<<<(BN_TOT*16)/256, 256, 0, stream>>>(out, stats, gamma, beta);
}

// Round 4
// 296.770 us; speedup vs baseline: 1.0273x; 1.0273x over previous
//
#include <hip/hip_runtime.h>

#define GS 128
#define GS3 (GS*GS*GS)
#define NPTS 150000
#define NBATCH 2
#define BN_TOT (NBATCH*NPTS)       // 300000
#define BN_PAD 300032              // 1172 conv blocks * 256 rows
#define ZROW   BN_PAD              // zero feature row
#define EPS 1e-5f
#define NBKT 8192                  // 2 batches * 16^3 coarse cells (8^3 blocks)

#define CONV_BLOCKS 1172

// ws layout (~78 MB)
#define OFF_GRID   0ull
#define SZ_GRID    ((size_t)NBATCH*GS3*4)            // 16,777,216
#define OFF_GRIDS  (OFF_GRID + SZ_GRID)              // sorted-id grid
#define OFF_WFRAG  (OFF_GRIDS + SZ_GRID)
#define SZ_WFRAG   ((size_t)27*4096*2)               // 221,184
#define OFF_STATS  (OFF_WFRAG + SZ_WFRAG)            // 512
#define OFF_CNT    (OFF_STATS + 512)                 // 32,768
#define OFF_CUR    (OFF_CNT + NBKT*4)                // 32,768
#define OFF_SIDX   (OFF_CUR + NBKT*4)                // 1,200,000
#define OFF_CSORT  (OFF_SIDX + 1200128)              // BN_PAD*16 = 4,800,512
#define OFF_FB16S  (OFF_CSORT + (size_t)BN_PAD*16)   // (BN_PAD+1)*128
#define SZ_FB16S   ((size_t)(BN_PAD+1)*128)

typedef __attribute__((ext_vector_type(8))) short bf16x8;
typedef __attribute__((ext_vector_type(4))) float f32x4;
typedef unsigned int u32;
typedef const __attribute__((address_space(1))) u32* gas_u32p;
typedef __attribute__((address_space(3))) u32* las_u32p;

__device__ __forceinline__ short f2bf(float f) {
    union { float f; unsigned u; } v; v.f = f;
    unsigned rr = v.u + 0x7fffu + ((v.u >> 16) & 1u);   // RNE
    return (short)(rr >> 16);
}

// ---------- kernel 1: grid scatter (orig pid) + bucket histogram ----------
__global__ __launch_bounds__(256) void k_count(const int* __restrict__ coords,
                                               int* __restrict__ grid,
                                               u32* __restrict__ cnt) {
    int p = blockIdx.x*256 + threadIdx.x;
    if (p >= BN_TOT) return;
    int x = coords[p*3+0], y = coords[p*3+1], z = coords[p*3+2];
    int b = (p >= NPTS);
    atomicMax(&grid[(b<<21) | (x<<14) | (y<<7) | z], p);
    atomicAdd(&cnt[(b<<12) | ((x>>3)<<8) | ((y>>3)<<4) | (z>>3)], 1u);
}

// ---------- kernel 2: exclusive scan of 8192 bucket counts -> cursors ----------
__global__ __launch_bounds__(1024) void k_scan(const u32* __restrict__ cnt,
                                               u32* __restrict__ cur) {
    __shared__ u32 ps[1024];
    int t = threadIdx.x;
    u32 l[8]; u32 s = 0;
    #pragma unroll
    for (int i = 0; i < 8; ++i) { l[i] = cnt[t*8+i]; s += l[i]; }
    ps[t] = s; __syncthreads();
    for (int off = 1; off < 1024; off <<= 1) {
        u32 v = (t >= off) ? ps[t-off] : 0u; __syncthreads();
        ps[t] += v; __syncthreads();
    }
    u32 run = (t == 0) ? 0u : ps[t-1];
    #pragma unroll
    for (int i = 0; i < 8; ++i) { cur[t*8+i] = run; run += l[i]; }
}

// ---------- kernel 3: place points in bucket order + bf16 features ----------
__global__ __launch_bounds__(256) void k_place(const float* __restrict__ feats,
                                               const int* __restrict__ coords,
                                               u32* __restrict__ cur,
                                               int* __restrict__ sortidx,
                                               int4* __restrict__ csorted,
                                               ushort* __restrict__ fb16s) {
    int p = blockIdx.x*256 + threadIdx.x;
    if (p >= BN_PAD) return;
    if (p >= BN_TOT) { csorted[p] = make_int4(-9,-9,-9,0); return; }   // pad rows
    int x = coords[p*3+0], y = coords[p*3+1], z = coords[p*3+2];
    int b = (p >= NPTS);
    int bkt = (b<<12) | ((x>>3)<<8) | ((y>>3)<<4) | (z>>3);
    int pos = (int)atomicAdd(&cur[bkt], 1u);
    sortidx[p] = pos;
    csorted[pos] = make_int4(x, y, z, p);
    const float4* s = (const float4*)(feats + (size_t)p*64);
    ushort* d = fb16s + (size_t)pos*64;
    #pragma unroll
    for (int i = 0; i < 8; ++i) {
        float4 a = s[2*i], c = s[2*i+1];
        ushort4 u0 = { (ushort)f2bf(a.x),(ushort)f2bf(a.y),(ushort)f2bf(a.z),(ushort)f2bf(a.w) };
        ushort4 u1 = { (ushort)f2bf(c.x),(ushort)f2bf(c.y),(ushort)f2bf(c.z),(ushort)f2bf(c.w) };
        ((ushort4*)d)[2*i] = u0; ((ushort4*)d)[2*i+1] = u1;
    }
}

// ---------- kernel 4: rewrite grid values to sorted indices ----------
__global__ __launch_bounds__(256) void k_regrid(const int* __restrict__ coords,
                                                const int* __restrict__ grid,
                                                const int* __restrict__ sortidx,
                                                int* __restrict__ gridS) {
    int p = blockIdx.x*256 + threadIdx.x;
    if (p >= BN_TOT) return;
    int x = coords[p*3+0], y = coords[p*3+1], z = coords[p*3+2];
    int b = (p >= NPTS);
    int cell = (b<<21) | (x<<14) | (y<<7) | z;
    if (grid[cell] == p) gridS[cell] = sortidx[p];     // winner (max orig pid) only
}

// ---------- kernel 5: weight -> bf16 MFMA B-fragments ----------
__global__ __launch_bounds__(256) void k_prefrag(const float* __restrict__ w,
                                                 short* __restrict__ wfrag) {
    int t = blockIdx.x * 256 + threadIdx.x;
    if (t >= 27*2*4*64*8) return;
    int i    = t & 7;
    int lane = (t >> 3) & 63;
    int tt   = (t >> 9) & 3;
    int c    = (t >> 11) & 1;
    int k    = t >> 12;
    int kk = c*32 + (lane >> 4)*8 + i;
    int co = tt*16 + (lane & 15);
    wfrag[t] = f2bf(w[(k*64 + kk)*64 + co]);
}

// ---------- kernel 6: gathered MFMA conv over SORTED rows ----------
// 8 waves/block; wave = 32 sorted rows x 64 cout. Grid probes + A-gathers are
// bucket-local (L1/L2-hot). W[k] double-buffered in LDS via global_load_lds,
// counted vmcnt(1): per iter issues [A x4, g x2, stage(k+1)] + stage(k)
// outstanding -> vmcnt(1) drains A+g+stage(k), keeps stage(k+1) in flight.
__global__ __launch_bounds__(512, 4) void k_conv(
    const ushort* __restrict__ fb16s,
    const int4* __restrict__ csorted,
    const int* __restrict__ gridS,
    const ushort* __restrict__ wfrag,
    float* __restrict__ out,
    float* __restrict__ gstats)
{
    __shared__ __align__(16) ushort bufs[2][4096];   // 2 x 8KB
    __shared__ float bsum[64], bsq[64];

    const int tid  = threadIdx.x;
    const int lane = tid & 63;
    const int wv   = tid >> 6;
    const int r    = lane & 15;
    const int seg  = lane >> 4;
    const int p0   = blockIdx.x * 256 + wv * 32;     // sorted row base

    const int4 c0 = csorted[p0 + r];
    const int4 c1 = csorted[p0 + 16 + r];
    const int gb0 = (c0.w >= NPTS) ? GS3 : 0;
    const int gb1 = (c1.w >= NPTS) ? GS3 : 0;

    // clamped, UNCONDITIONAL probe of the sorted-id grid
    auto lk = [&](int gb, int cx, int cy, int cz, int kk) -> int {
        int dx = kk/9 - 1, dy = (kk/3)%3 - 1, dz = kk%3 - 1;
        int nx = cx+dx, ny = cy+dy, nz = cz+dz;
        int ok = (int)(((unsigned)nx < 128u) & ((unsigned)ny < 128u) &
                       ((unsigned)nz < 128u));
        int id = gridS[gb + ((nx&127)<<14) + ((ny&127)<<7) + (nz&127)];
        return ok ? id : -1;
    };

    auto stage = [&](int kk, int bsel) {
        const u32* g = (const u32*)(wfrag + (size_t)kk*4096 + tid*8);
        u32* l = (u32*)(&bufs[bsel][wv*512]);
        __builtin_amdgcn_global_load_lds((gas_u32p)g, (las_u32p)l, 16, 0, 0);
    };

    f32x4 c00={0,0,0,0}, c01={0,0,0,0}, c02={0,0,0,0}, c03={0,0,0,0};
    f32x4 c10={0,0,0,0}, c11={0,0,0,0}, c12={0,0,0,0}, c13={0,0,0,0};

    stage(0, 0);
    int s0 = lk(gb0, c0.x, c0.y, c0.z, 0);
    int s1 = lk(gb1, c1.x, c1.y, c1.z, 0);

    #pragma unroll 1
    for (int k = 0; k < 27; ++k) {
        const ushort* a0p = fb16s + (size_t)(s0 < 0 ? ZROW : s0)*64 + seg*8;
        const ushort* a1p = fb16s + (size_t)(s1 < 0 ? ZROW : s1)*64 + seg*8;
        bf16x8 a00 = *(const bf16x8*)(a0p);
        bf16x8 a01 = *(const bf16x8*)(a0p + 32);
        bf16x8 a10 = *(const bf16x8*)(a1p);
        bf16x8 a11 = *(const bf16x8*)(a1p + 32);
        const bool v0 = (s0 >= 0), v1 = (s1 >= 0);

        int kn = (k == 26) ? 0 : k+1;                 // dummy at tail keeps counts uniform
        int g0n = lk(gb0, c0.x, c0.y, c0.z, kn);
        int g1n = lk(gb1, c1.x, c1.y, c1.z, kn);
        stage(kn, (k+1)&1);

        const bf16x8 zz = {0,0,0,0,0,0,0,0};
        if (!v0) { a00 = zz; a01 = zz; }
        if (!v1) { a10 = zz; a11 = zz; }

        asm volatile("s_waitcnt vmcnt(1)" ::: "memory");
        __builtin_amdgcn_s_barrier();
        __builtin_amdgcn_sched_barrier(0);

        const bool any0 = __any(v0), any1 = __any(v1);
        if (any0 | any1) {
            const bf16x8* bb = (const bf16x8*)bufs[k&1];
            bf16x8 b00 = bb[0*64+lane], b01 = bb[1*64+lane],
                   b02 = bb[2*64+lane], b03 = bb[3*64+lane],
                   b10 = bb[4*64+lane], b11 = bb[5*64+lane],
                   b12 = bb[6*64+lane], b13 = bb[7*64+lane];
            if (any0) {
                c00 = __builtin_amdgcn_mfma_f32_16x16x32_bf16(a00, b00, c00, 0,0,0);
                c01 = __builtin_amdgcn_mfma_f32_16x16x32_bf16(a00, b01, c01, 0,0,0);
                c02 = __builtin_amdgcn_mfma_f32_16x16x32_bf16(a00, b02, c02, 0,0,0);
                c03 = __builtin_amdgcn_mfma_f32_16x16x32_bf16(a00, b03, c03, 0,0,0);
                c00 = __builtin_amdgcn_mfma_f32_16x16x32_bf16(a01, b10, c00, 0,0,0);
                c01 = __builtin_amdgcn_mfma_f32_16x16x32_bf16(a01, b11, c01, 0,0,0);
                c02 = __builtin_amdgcn_mfma_f32_16x16x32_bf16(a01, b12, c02, 0,0,0);
                c03 = __builtin_amdgcn_mfma_f32_16x16x32_bf16(a01, b13, c03, 0,0,0);
            }
            if (any1) {
                c10 = __builtin_amdgcn_mfma_f32_16x16x32_bf16(a10, b00, c10, 0,0,0);
                c11 = __builtin_amdgcn_mfma_f32_16x16x32_bf16(a10, b01, c11, 0,0,0);
                c12 = __builtin_amdgcn_mfma_f32_16x16x32_bf16(a10, b02, c12, 0,0,0);
                c13 = __builtin_amdgcn_mfma_f32_16x16x32_bf16(a10, b03, c13, 0,0,0);
                c10 = __builtin_amdgcn_mfma_f32_16x16x32_bf16(a11, b10, c10, 0,0,0);
                c11 = __builtin_amdgcn_mfma_f32_16x16x32_bf16(a11, b11, c11, 0,0,0);
                c12 = __builtin_amdgcn_mfma_f32_16x16x32_bf16(a11, b12, c12, 0,0,0);
                c13 = __builtin_amdgcn_mfma_f32_16x16x32_bf16(a11, b13, c13, 0,0,0);
            }
        }
        __builtin_amdgcn_sched_barrier(0);
        __builtin_amdgcn_s_barrier();
        s0 = g0n; s1 = g1n;
    }

    // epilogue: scatter rows to out[orig pid].  C/D: col=lane&15, row=(lane>>4)*4+j
    const int* cw = (const int*)csorted;
    #pragma unroll
    for (int j = 0; j < 4; ++j) {
        int row0 = p0 + seg*4 + j;
        if (row0 < BN_TOT) {
            int opid = cw[(size_t)row0*4 + 3];
            float* ob = out + (size_t)opid*64 + r;
            ob[ 0] = c00[j]; ob[16] = c01[j]; ob[32] = c02[j]; ob[48] = c03[j];
        }
        int row1 = p0 + 16 + seg*4 + j;
        if (row1 < BN_TOT) {
            int opid = cw[(size_t)row1*4 + 3];
            float* ob = out + (size_t)opid*64 + r;
            ob[ 0] = c10[j]; ob[16] = c11[j]; ob[32] = c12[j]; ob[48] = c13[j];
        }
    }

    // fused stats (pad rows have zero accumulators)
    if (tid < 64) { bsum[tid] = 0.f; bsq[tid] = 0.f; }
    __syncthreads();
    float s_[4] = {0,0,0,0}, q_[4] = {0,0,0,0};
    #pragma unroll
    for (int j = 0; j < 4; ++j) {
        s_[0] += c00[j] + c10[j];  q_[0] += c00[j]*c00[j] + c10[j]*c10[j];
        s_[1] += c01[j] + c11[j];  q_[1] += c01[j]*c01[j] + c11[j]*c11[j];
        s_[2] += c02[j] + c12[j];  q_[2] += c02[j]*c02[j] + c12[j]*c12[j];
        s_[3] += c03[j] + c13[j];  q_[3] += c03[j]*c03[j] + c13[j]*c13[j];
    }
    #pragma unroll
    for (int q = 0; q < 4; ++q) {
        atomicAdd(&bsum[q*16 + r], s_[q]);
        atomicAdd(&bsq [q*16 + r], q_[q]);
    }
    __syncthreads();
    if (tid < 64) { atomicAdd(&gstats[tid], bsum[tid]); atomicAdd(&gstats[64+tid], bsq[tid]); }
}

// ---------- kernel 7: normalize + affine + ReLU, in place ----------
__global__ __launch_bounds__(256) void k_norm(float* __restrict__ out,
                                              const float* __restrict__ stats,
                                              const float* __restrict__ gamma,
                                              const float* __restrict__ beta) {
    int i = blockIdx.x*256 + threadIdx.x;
    const int n4 = BN_TOT*16;
    if (i >= n4) return;
    float4 v = ((const float4*)out)[i];
    int ch = (i & 15) * 4;
    float o[4] = {v.x, v.y, v.z, v.w};
    float rp[4];
    #pragma unroll
    for (int j = 0; j < 4; ++j) {
        int c = ch + j;
        float mean = stats[c] * (1.f/BN_TOT);
        float var  = stats[64+c] * (1.f/BN_TOT) - mean*mean;
        float y = (o[j] - mean) * rsqrtf(var + EPS) * gamma[c] + beta[c];
        rp[j] = fmaxf(y, 0.f);
    }
    float4 rv; rv.x = rp[0]; rv.y = rp[1]; rv.z = rp[2]; rv.w = rp[3];
    ((float4*)out)[i] = rv;
}

extern "C" void kernel_launch(void* const* d_in, const int* in_sizes, int n_in,
                              void* d_out, int out_size, void* d_ws, size_t ws_size,
                              hipStream_t stream) {
    const float* feats  = (const float*)d_in[0];
    const int*   coords = (const int*)d_in[1];
    const float* weight = (const float*)d_in[2];
    const float* gamma  = (const float*)d_in[3];
    const float* beta   = (const float*)d_in[4];
    float* out = (float*)d_out;

    char*   ws      = (char*)d_ws;
    int*    grid    = (int*)(ws + OFF_GRID);
    int*    gridS   = (int*)(ws + OFF_GRIDS);
    short*  wfrag   = (short*)(ws + OFF_WFRAG);
    float*  stats   = (float*)(ws + OFF_STATS);
    u32*    cnt     = (u32*)(ws + OFF_CNT);
    u32*    cur     = (u32*)(ws + OFF_CUR);
    int*    sortidx = (int*)(ws + OFF_SIDX);
    int4*   csorted = (int4*)(ws + OFF_CSORT);
    ushort* fb16s   = (ushort*)(ws + OFF_FB16S);

    hipMemsetAsync(grid,  0xFF, SZ_GRID, stream);
    hipMemsetAsync(gridS, 0xFF, SZ_GRID, stream);
    hipMemsetAsync(stats, 0, 512, stream);
    hipMemsetAsync(cnt,   0, NBKT*4, stream);
    hipMemsetAsync(fb16s + (size_t)BN_TOT*64, 0,
                   (size_t)(BN_PAD + 1 - BN_TOT)*128, stream);   // pad + zero row

    k_count <<<(BN_TOT + 255)/256, 256, 0, stream>>>(coords, grid, cnt);
    k_scan  <<<1, 1024, 0, stream>>>(cnt, cur);
    k_place <<<(BN_PAD + 255)/256, 256, 0, stream>>>(feats, coords, cur,
                                                     sortidx, csorted, fb16s);
    k_regrid<<<(BN_TOT + 255)/256, 256, 0, stream>>>(coords, grid, sortidx, gridS);
    k_prefrag<<<(27*2*4*64*8)/256, 256, 0, stream>>>(weight, wfrag);
    k_conv  <<<CONV_BLOCKS, 512, 0, stream>>>(fb16s, csorted, gridS,
                                              (const ushort*)wfrag, out, stats);
    k_norm  <<<(BN_TOT*16)/256, 256, 0, stream>>>(out, stats, gamma, beta);
}

// Round 5
// 270.353 us; speedup vs baseline: 1.1277x; 1.0977x over previous
//
#include <hip/hip_runtime.h>

#define GS 128
#define GS3 (GS*GS*GS)
#define NPTS 150000
#define NBATCH 2
#define BN_TOT (NBATCH*NPTS)       // 300000
#define CONV_BLOCKS 2344           // 128 rows/block
#define BN_PAD (CONV_BLOCKS*128)   // 300032
#define ZROW   BN_PAD              // zero feature row index
#define EPS 1e-5f
#define NBKT 8192                  // 2 batches * 16^3 coarse buckets (8^3 cells)

// ws layout (~94 MB)
#define OFF_GRID   0ull
#define SZ_GRID    ((size_t)NBATCH*GS3*4)            // 16,777,216
#define OFF_WFRAG  (OFF_GRID + SZ_GRID)
#define SZ_WFRAG   ((size_t)27*4096*2)               // 221,184
#define OFF_STATS  (OFF_WFRAG + SZ_WFRAG)            // 512
#define OFF_CNT    (OFF_STATS + 512)                 // 32,768
#define OFF_CUR    (OFF_CNT + NBKT*4)                // 32,768
#define OFF_SIDX   (OFF_CUR + NBKT*4)                // 1,200,000
#define OFF_CSORT  (OFF_SIDX + 1200128)              // BN_PAD*16
#define OFF_FB16S  (OFF_CSORT + (size_t)BN_PAD*16)   // (BN_PAD+1)*128
#define OFF_IDS    (OFF_FB16S + (size_t)(BN_PAD+1)*128)  // 27*BN_PAD*4 = 32.4MB

typedef __attribute__((ext_vector_type(8))) short bf16x8;
typedef __attribute__((ext_vector_type(4))) float f32x4;
typedef unsigned int u32;
typedef const __attribute__((address_space(1))) u32* gas_u32p;
typedef __attribute__((address_space(3))) u32* las_u32p;

__device__ __forceinline__ short f2bf(float f) {
    union { float f; unsigned u; } v; v.f = f;
    unsigned rr = v.u + 0x7fffu + ((v.u >> 16) & 1u);   // RNE
    return (short)(rr >> 16);
}

// ---------- kernel 1: grid scatter (max orig pid) + bucket histogram ----------
__global__ __launch_bounds__(256) void k_count(const int* __restrict__ coords,
                                               int* __restrict__ grid,
                                               u32* __restrict__ cnt) {
    int p = blockIdx.x*256 + threadIdx.x;
    if (p >= BN_TOT) return;
    int x = coords[p*3+0], y = coords[p*3+1], z = coords[p*3+2];
    int b = (p >= NPTS);
    atomicMax(&grid[(b<<21) | (x<<14) | (y<<7) | z], p);
    atomicAdd(&cnt[(b<<12) | ((x>>3)<<8) | ((y>>3)<<4) | (z>>3)], 1u);
}

// ---------- kernel 2: exclusive scan of 8192 bucket counts ----------
__global__ __launch_bounds__(1024) void k_scan(const u32* __restrict__ cnt,
                                               u32* __restrict__ cur) {
    __shared__ u32 ps[1024];
    int t = threadIdx.x;
    u32 l[8]; u32 s = 0;
    #pragma unroll
    for (int i = 0; i < 8; ++i) { l[i] = cnt[t*8+i]; s += l[i]; }
    ps[t] = s; __syncthreads();
    for (int off = 1; off < 1024; off <<= 1) {
        u32 v = (t >= off) ? ps[t-off] : 0u; __syncthreads();
        ps[t] += v; __syncthreads();
    }
    u32 run = (t == 0) ? 0u : ps[t-1];
    #pragma unroll
    for (int i = 0; i < 8; ++i) { cur[t*8+i] = run; run += l[i]; }
}

// ---------- kernel 3: place points in bucket order + bf16 features ----------
__global__ __launch_bounds__(256) void k_place(const float* __restrict__ feats,
                                               const int* __restrict__ coords,
                                               u32* __restrict__ cur,
                                               int* __restrict__ sortidx,
                                               int4* __restrict__ csorted,
                                               ushort* __restrict__ fb16s) {
    int p = blockIdx.x*256 + threadIdx.x;
    if (p >= BN_PAD) return;
    if (p >= BN_TOT) { csorted[p] = make_int4(-9,-9,-9,0); return; }
    int x = coords[p*3+0], y = coords[p*3+1], z = coords[p*3+2];
    int b = (p >= NPTS);
    int bkt = (b<<12) | ((x>>3)<<8) | ((y>>3)<<4) | (z>>3);
    int pos = (int)atomicAdd(&cur[bkt], 1u);
    sortidx[p] = pos;
    csorted[pos] = make_int4(x, y, z, p);
    const float4* s = (const float4*)(feats + (size_t)p*64);
    ushort* d = fb16s + (size_t)pos*64;
    #pragma unroll
    for (int i = 0; i < 8; ++i) {
        float4 a = s[2*i], c = s[2*i+1];
        ushort4 u0 = { (ushort)f2bf(a.x),(ushort)f2bf(a.y),(ushort)f2bf(a.z),(ushort)f2bf(a.w) };
        ushort4 u1 = { (ushort)f2bf(c.x),(ushort)f2bf(c.y),(ushort)f2bf(c.z),(ushort)f2bf(c.w) };
        ((ushort4*)d)[2*i] = u0; ((ushort4*)d)[2*i+1] = u1;
    }
}

// ---------- kernel 4: rulebook — 27 sorted-id refs per sorted row ----------
// ids[k][s] = sorted row index feeding output row s at offset k; ZROW if none.
__global__ __launch_bounds__(256) void k_ids(const int4* __restrict__ csorted,
                                             const int* __restrict__ grid,
                                             const int* __restrict__ sortidx,
                                             int* __restrict__ ids) {
    int s = blockIdx.x*256 + threadIdx.x;
    if (s >= BN_PAD) return;
    int4 c = csorted[s];
    const bool pad = (s >= BN_TOT);
    const int gb = (c.w >= NPTS) ? GS3 : 0;
    #pragma unroll
    for (int k = 0; k < 27; ++k) {
        int dx = k/9 - 1, dy = (k/3)%3 - 1, dz = k%3 - 1;   // compile-time
        int nx = c.x+dx, ny = c.y+dy, nz = c.z+dz;
        int sid = ZROW;
        if (!pad && (((unsigned)nx < 128u) & ((unsigned)ny < 128u) &
                     ((unsigned)nz < 128u))) {
            int pid = grid[gb + (nx<<14) + (ny<<7) + nz];
            if (pid >= 0) sid = sortidx[pid];
        }
        ids[(size_t)k*BN_PAD + s] = sid;
    }
}

// ---------- kernel 5: weight -> bf16 MFMA B-fragments ----------
__global__ __launch_bounds__(256) void k_prefrag(const float* __restrict__ w,
                                                 short* __restrict__ wfrag) {
    int t = blockIdx.x * 256 + threadIdx.x;
    if (t >= 27*2*4*64*8) return;
    int i    = t & 7;
    int lane = (t >> 3) & 63;
    int tt   = (t >> 9) & 3;
    int c    = (t >> 11) & 1;
    int k    = t >> 12;
    int kk = c*32 + (lane >> 4)*8 + i;
    int co = tt*16 + (lane & 15);
    wfrag[t] = f2bf(w[(k*64 + kk)*64 + co]);
}

// ---------- kernel 6: pipelined gathered MFMA conv ----------
// 4 waves/block, wave = 32 sorted rows x 64 cout. Per-block ids in LDS.
// Steady phase k: vmcnt(4) [drains stage(k)+A(k), keeps A(k+1) flying],
// ONE s_barrier, ds_read B(k), issue stage(k+1), 16 MFMA, issue A(k+2).
__global__ __launch_bounds__(256, 3) void k_conv(
    const ushort* __restrict__ fb16s,
    const int4* __restrict__ csorted,
    const int* __restrict__ ids_g,
    const ushort* __restrict__ wfrag,
    float* __restrict__ out,
    float* __restrict__ gstats)
{
    __shared__ __align__(16) ushort ldsB[2][4096];   // 2 x 8KB B double-buffer
    __shared__ int ids_lds[27*128];                  // 13.8KB block rulebook
    __shared__ float bsum[64], bsq[64];

    const int tid  = threadIdx.x;
    const int lane = tid & 63;
    const int wv   = tid >> 6;
    const int r    = lane & 15;
    const int seg  = lane >> 4;
    const int p0b  = blockIdx.x * 128;       // block's sorted-row base
    const int wrow = wv*32 + r;              // lane's tile0 row within block

    auto stage = [&](int kk, int bsel) {
        const u32* g = (const u32*)(wfrag + (size_t)kk*4096) + tid*4;
        u32* l  = (u32*)(&ldsB[bsel][wv*512]);
        __builtin_amdgcn_global_load_lds((gas_u32p)g,  (las_u32p)l,  16, 0, 0);
        const u32* g2 = g + 1024;                       // +4KB
        u32* l2 = (u32*)(&ldsB[bsel][2048 + wv*512]);
        __builtin_amdgcn_global_load_lds((gas_u32p)g2, (las_u32p)l2, 16, 0, 0);
    };

#define LDA4(AC, sid0, sid1) {                                            \
        const ushort* a0_ = fb16s + (size_t)(sid0)*64 + seg*8;            \
        const ushort* a1_ = fb16s + (size_t)(sid1)*64 + seg*8;            \
        AC[0] = *(const bf16x8*)(a0_);  AC[1] = *(const bf16x8*)(a0_+32); \
        AC[2] = *(const bf16x8*)(a1_);  AC[3] = *(const bf16x8*)(a1_+32); }

    f32x4 t0q0={0,0,0,0}, t0q1={0,0,0,0}, t0q2={0,0,0,0}, t0q3={0,0,0,0};
    f32x4 t1q0={0,0,0,0}, t1q1={0,0,0,0}, t1q2={0,0,0,0}, t1q3={0,0,0,0};
    bf16x8 aE[4], aO[4];

    // ---- prologue ----
    #pragma unroll
    for (int c = 0; c < 14; ++c) {
        int idx = c*256 + tid;
        if (idx < 27*128)
            ids_lds[idx] = ids_g[(size_t)(idx>>7)*BN_PAD + p0b + (idx&127)];
    }
    int i00 = ids_g[p0b + wrow];
    int i01 = ids_g[p0b + wrow + 16];
    int i10 = ids_g[(size_t)BN_PAD + p0b + wrow];
    int i11 = ids_g[(size_t)BN_PAD + p0b + wrow + 16];
    __syncthreads();                          // ids_lds ready; drains all vmem
    __builtin_amdgcn_sched_barrier(0);
    LDA4(aE, i00, i01);                       // A(0) x4
    __builtin_amdgcn_sched_barrier(0);
    stage(0, 0);                              // stage(0) x2
    __builtin_amdgcn_sched_barrier(0);
    LDA4(aO, i10, i11);                       // A(1) x4
    __builtin_amdgcn_sched_barrier(0);
    // invariant entering phase 0: outstanding = [A(0)x4, stage(0)x2, A(1)x4]

    auto phase = [&](int k, bf16x8 (&AC)[4], int bsel) {
        asm volatile("s_waitcnt vmcnt(4)" ::: "memory");
        __builtin_amdgcn_sched_barrier(0);
        __builtin_amdgcn_s_barrier();
        __builtin_amdgcn_sched_barrier(0);
        const bf16x8* bb = (const bf16x8*)ldsB[bsel];
        bf16x8 b0 = bb[0*64+lane], b1 = bb[1*64+lane],
               b2 = bb[2*64+lane], b3 = bb[3*64+lane],
               b4 = bb[4*64+lane], b5 = bb[5*64+lane],
               b6 = bb[6*64+lane], b7 = bb[7*64+lane];
        int kp2 = (k+2 > 26) ? 26 : k+2;
        int idn0 = ids_lds[kp2*128 + wrow];
        int idn1 = ids_lds[kp2*128 + wrow + 16];
        if (k < 26) stage(k+1, bsel^1);
        __builtin_amdgcn_sched_barrier(0);
        t0q0 = __builtin_amdgcn_mfma_f32_16x16x32_bf16(AC[0], b0, t0q0, 0,0,0);
        t0q1 = __builtin_amdgcn_mfma_f32_16x16x32_bf16(AC[0], b1, t0q1, 0,0,0);
        t0q2 = __builtin_amdgcn_mfma_f32_16x16x32_bf16(AC[0], b2, t0q2, 0,0,0);
        t0q3 = __builtin_amdgcn_mfma_f32_16x16x32_bf16(AC[0], b3, t0q3, 0,0,0);
        t0q0 = __builtin_amdgcn_mfma_f32_16x16x32_bf16(AC[1], b4, t0q0, 0,0,0);
        t0q1 = __builtin_amdgcn_mfma_f32_16x16x32_bf16(AC[1], b5, t0q1, 0,0,0);
        t0q2 = __builtin_amdgcn_mfma_f32_16x16x32_bf16(AC[1], b6, t0q2, 0,0,0);
        t0q3 = __builtin_amdgcn_mfma_f32_16x16x32_bf16(AC[1], b7, t0q3, 0,0,0);
        t1q0 = __builtin_amdgcn_mfma_f32_16x16x32_bf16(AC[2], b0, t1q0, 0,0,0);
        t1q1 = __builtin_amdgcn_mfma_f32_16x16x32_bf16(AC[2], b1, t1q1, 0,0,0);
        t1q2 = __builtin_amdgcn_mfma_f32_16x16x32_bf16(AC[2], b2, t1q2, 0,0,0);
        t1q3 = __builtin_amdgcn_mfma_f32_16x16x32_bf16(AC[2], b3, t1q3, 0,0,0);
        t1q0 = __builtin_amdgcn_mfma_f32_16x16x32_bf16(AC[3], b4, t1q0, 0,0,0);
        t1q1 = __builtin_amdgcn_mfma_f32_16x16x32_bf16(AC[3], b5, t1q1, 0,0,0);
        t1q2 = __builtin_amdgcn_mfma_f32_16x16x32_bf16(AC[3], b6, t1q2, 0,0,0);
        t1q3 = __builtin_amdgcn_mfma_f32_16x16x32_bf16(AC[3], b7, t1q3, 0,0,0);
        __builtin_amdgcn_sched_barrier(0);
        if (k < 26) { LDA4(AC, idn0, idn1); }   // issue A(k+2) into freed regs
        __builtin_amdgcn_sched_barrier(0);
    };

    #pragma unroll 1
    for (int t = 0; t < 13; ++t) {
        phase(2*t,   aE, 0);
        phase(2*t+1, aO, 1);
    }
    phase(26, aE, 0);

    // ---- epilogue: scatter to out[orig pid]; C/D col=lane&15, row=seg*4+j ----
    #pragma unroll
    for (int j = 0; j < 4; ++j) {
        int row0 = p0b + wv*32 + seg*4 + j;
        if (row0 < BN_TOT) {
            int opid = csorted[row0].w;
            float* ob = out + (size_t)opid*64 + r;
            ob[ 0] = t0q0[j]; ob[16] = t0q1[j]; ob[32] = t0q2[j]; ob[48] = t0q3[j];
        }
        int row1 = row0 + 16;
        if (row1 < BN_TOT) {
            int opid = csorted[row1].w;
            float* ob = out + (size_t)opid*64 + r;
            ob[ 0] = t1q0[j]; ob[16] = t1q1[j]; ob[32] = t1q2[j]; ob[48] = t1q3[j];
        }
    }

    // ---- fused stats (pad rows contribute exact zeros) ----
    if (tid < 64) { bsum[tid] = 0.f; bsq[tid] = 0.f; }
    __syncthreads();
    float s0=0,s1=0,s2=0,s3=0,q0=0,q1=0,q2=0,q3=0;
    #pragma unroll
    for (int j = 0; j < 4; ++j) {
        s0 += t0q0[j] + t1q0[j];  q0 += t0q0[j]*t0q0[j] + t1q0[j]*t1q0[j];
        s1 += t0q1[j] + t1q1[j];  q1 += t0q1[j]*t0q1[j] + t1q1[j]*t1q1[j];
        s2 += t0q2[j] + t1q2[j];  q2 += t0q2[j]*t0q2[j] + t1q2[j]*t1q2[j];
        s3 += t0q3[j] + t1q3[j];  q3 += t0q3[j]*t0q3[j] + t1q3[j]*t1q3[j];
    }
    atomicAdd(&bsum[ 0 + r], s0);  atomicAdd(&bsq[ 0 + r], q0);
    atomicAdd(&bsum[16 + r], s1);  atomicAdd(&bsq[16 + r], q1);
    atomicAdd(&bsum[32 + r], s2);  atomicAdd(&bsq[32 + r], q2);
    atomicAdd(&bsum[48 + r], s3);  atomicAdd(&bsq[48 + r], q3);
    __syncthreads();
    if (tid < 64) { atomicAdd(&gstats[tid], bsum[tid]); atomicAdd(&gstats[64+tid], bsq[tid]); }
#undef LDA4
}

// ---------- kernel 7: normalize + affine + ReLU, in place ----------
__global__ __launch_bounds__(256) void k_norm(float* __restrict__ out,
                                              const float* __restrict__ stats,
                                              const float* __restrict__ gamma,
                                              const float* __restrict__ beta) {
    int i = blockIdx.x*256 + threadIdx.x;
    const int n4 = BN_TOT*16;
    if (i >= n4) return;
    float4 v = ((const float4*)out)[i];
    int ch = (i & 15) * 4;
    float o[4] = {v.x, v.y, v.z, v.w};
    float rp[4];
    #pragma unroll
    for (int j = 0; j < 4; ++j) {
        int c = ch + j;
        float mean = stats[c] * (1.f/BN_TOT);
        float var  = stats[64+c] * (1.f/BN_TOT) - mean*mean;
        float y = (o[j] - mean) * rsqrtf(var + EPS) * gamma[c] + beta[c];
        rp[j] = fmaxf(y, 0.f);
    }
    float4 rv; rv.x = rp[0]; rv.y = rp[1]; rv.z = rp[2]; rv.w = rp[3];
    ((float4*)out)[i] = rv;
}

extern "C" void kernel_launch(void* const* d_in, const int* in_sizes, int n_in,
                              void* d_out, int out_size, void* d_ws, size_t ws_size,
                              hipStream_t stream) {
    const float* feats  = (const float*)d_in[0];
    const int*   coords = (const int*)d_in[1];
    const float* weight = (const float*)d_in[2];
    const float* gamma  = (const float*)d_in[3];
    const float* beta   = (const float*)d_in[4];
    float* out = (float*)d_out;

    char*   ws      = (char*)d_ws;
    int*    grid    = (int*)(ws + OFF_GRID);
    short*  wfrag   = (short*)(ws + OFF_WFRAG);
    float*  stats   = (float*)(ws + OFF_STATS);
    u32*    cnt     = (u32*)(ws + OFF_CNT);
    u32*    cur     = (u32*)(ws + OFF_CUR);
    int*    sortidx = (int*)(ws + OFF_SIDX);
    int4*   csorted = (int4*)(ws + OFF_CSORT);
    ushort* fb16s   = (ushort*)(ws + OFF_FB16S);
    int*    idbuf   = (int*)(ws + OFF_IDS);

    hipMemsetAsync(grid,  0xFF, SZ_GRID, stream);
    hipMemsetAsync(stats, 0, 512, stream);
    hipMemsetAsync(cnt,   0, NBKT*4, stream);
    hipMemsetAsync(fb16s + (size_t)BN_TOT*64, 0,
                   (size_t)(BN_PAD + 1 - BN_TOT)*128, stream);   // pads + ZROW

    k_count  <<<(BN_TOT + 255)/256, 256, 0, stream>>>(coords, grid, cnt);
    k_scan   <<<1, 1024, 0, stream>>>(cnt, cur);
    k_place  <<<(BN_PAD + 255)/256, 256, 0, stream>>>(feats, coords, cur,
                                                      sortidx, csorted, fb16s);
    k_ids    <<<(BN_PAD + 255)/256, 256, 0, stream>>>(csorted, grid, sortidx, idbuf);
    k_prefrag<<<(27*2*4*64*8)/256, 256, 0, stream>>>(weight, wfrag);
    k_conv   <<<CONV_BLOCKS, 256, 0, stream>>>(fb16s, csorted, idbuf,
                                               (const ushort*)wfrag, out, stats);
    k_norm   <<<(BN_TOT*16)/256, 256, 0, stream>>>(out, stats, gamma, beta);
}